// Round 1
// baseline (159.599 us; speedup 1.0000x reference)
//
#include <hip/hip_runtime.h>
#include <hip/hip_bf16.h>
#include <math.h>

#define B_DIM 8
#define C_DIM 32
#define N_DIM 4096
#define KSL 2048           // k per kh-group
#define NCH (KSL / 32)     // 64 chunks

typedef short bf16x8 __attribute__((ext_vector_type(8)));   // 8 bf16 = 4 VGPRs
typedef float f32x4 __attribute__((ext_vector_type(4)));
typedef unsigned int uint4v __attribute__((ext_vector_type(4)));
typedef unsigned short ushort8 __attribute__((ext_vector_type(8)));

__device__ __forceinline__ ushort f2bf_rne(float f) {
  unsigned u = __float_as_uint(f);
  u += 0x7FFF + ((u >> 16) & 1);
  return (ushort)(u >> 16);
}

// Prep A: E[b,n] = exp(mean_c x[b,c,n]).  Hot loop uses the exact identity
// 2*sigmoid(-|ck-cm|) = 2*min(Ek,Em)/(Ek+Em).
__global__ __launch_bounds__(256) void prep_e(const float* __restrict__ x,
                                              float* __restrict__ E) {
  int idx = blockIdx.x * 256 + threadIdx.x;   // 0 .. B*N-1
  int b = idx >> 12;
  int n = idx & (N_DIM - 1);
  const float* p = x + (size_t)b * C_DIM * N_DIM + n;
  float s = 0.f;
#pragma unroll
  for (int c = 0; c < C_DIM; ++c) s += p[(size_t)c * N_DIM];
  E[idx] = __builtin_amdgcn_exp2f(s * (1.44269504f / C_DIM));
}

// Prep B: feabT tiled bf16: feabT[((b*128 + n/32)*32 + c)*32 + n%32]
__global__ __launch_bounds__(256) void prep_feab(const float* __restrict__ x,
                                                 ushort* __restrict__ feabT) {
  int idx = blockIdx.x * 256 + threadIdx.x;   // 0 .. 8*32*256-1
  int g = idx & 255;           // n-group of 16
  int c = (idx >> 8) & 31;
  int b = idx >> 13;
  int n0 = g * 16;
  const float* p = x + ((size_t)(b * C_DIM + c)) * N_DIM + n0;
  ushort* q = feabT + ((size_t)(b * (N_DIM / 32) + (n0 >> 5)) * C_DIM + c) * 32 + (n0 & 31);
  ushort8 v0, v1;
#pragma unroll
  for (int j = 0; j < 8; ++j) v0[j] = f2bf_rne(p[j]);
#pragma unroll
  for (int j = 0; j < 8; ++j) v1[j] = f2bf_rne(p[8 + j]);
  *(ushort8*)q = v0;
  *(ushort8*)(q + 8) = v1;
}

// Fused kernel, restructured K-loop pipeline:
//  - adj tile double-buffered per kh-group (abuf[kh][parity]) -> ONE raw
//    s_barrier per chunk with lgkmcnt-only wait: global loads stay in flight
//    across the barrier (no vmcnt drain).
//  - adj tile stored transposed [col][k] with stride 36: staging writes are
//    2-way (free), fragment reads are 2x ds_read_b128, bank-balanced.
//  - fa/ek register prefetch one chunk ahead (A/B role swap, no rotate movs).
//  - pairwise rcp (1 trans + 3 mul per pair instead of 2 trans).
//  - the uniform x2 of the weight is folded into the epilogue (para*2).
__global__ __launch_bounds__(1024, 4) void gcn_fused(
    const ushort* __restrict__ feabT, const float* __restrict__ adj,
    const float* __restrict__ E, const float* __restrict__ para,
    float* __restrict__ out) {
  __shared__ __align__(16) float abuf[2][2][16 * 36];  // kh x parity x tile, 9.2 KB
  __shared__ float red[B_DIM][544];                    // stride 17, 17.4 KB

  const int tid = threadIdx.x;
  const int lane = tid & 63;
  const int w = tid >> 6;           // 0..15
  const int b = w & 7;              // batch
  const int kh = w >> 3;            // 0..1 = K-half
  const int quad = lane >> 4;
  const int l15 = lane & 15;
  const int colgrp = blockIdx.x;    // 0..255
  const int col = colgrp * 16 + l15;
  const int ksbase = kh * KSL;

  // staging: each kh-group's 512 threads cover its 32x16 tile, 1 elem each.
  // write transposed: tile[col][k], stride 36 words.
  const int tg = tid & 511;
  const float* agp = adj + (size_t)(ksbase + (tg >> 4)) * N_DIM + colgrp * 16 + (tg & 15);
  const int swaddr = (tg & 15) * 36 + (tg >> 4);

  const float* Eb = E + (size_t)b * N_DIM;
  const float Em = Eb[col];
  const float* ekb = Eb + ksbase + quad * 8;
  const ushort* fb = feabT + ((size_t)b * (N_DIM / 32) + (ksbase >> 5)) * (C_DIM * 32);

  float(&grp)[2][16 * 36] = abuf[kh];

  f32x4 acc0 = {0.f, 0.f, 0.f, 0.f};   // channels 0-15
  f32x4 acc1 = {0.f, 0.f, 0.f, 0.f};   // channels 16-31

  // adj staging pipeline: tile0 -> LDS buf0; tile1 -> a_nxt (reg)
  float a_nxt, a_nx2;
  {
    const float a0 = agp[0];
    a_nxt = agp[(size_t)32 * N_DIM];
    grp[0][swaddr] = a0;
  }

  // chunk-0 register prefetch (A buffers)
  bf16x8 f0A = *(const bf16x8*)(fb + l15 * 32 + quad * 8);
  bf16x8 f1A = *(const bf16x8*)(fb + (16 + l15) * 32 + quad * 8);
  float eA[8], eB[8];
  *(f32x4*)&eA[0] = *(const f32x4*)(ekb);
  *(f32x4*)&eA[4] = *(const f32x4*)(ekb + 4);
  bf16x8 f0B, f1B;

  // tile0 visible to the group; global loads NOT drained.
  asm volatile("s_waitcnt lgkmcnt(0)\n\ts_barrier" ::: "memory");

  auto step = [&](const int ch, const int p, const bf16x8 cf0, const bf16x8 cf1,
                  const float(&ce)[8], bf16x8& nf0, bf16x8& nf1, float(&ne)[8]) {
    // issue staging load for tile ch+2 (arrives >= 1 full chunk before use)
    if (ch + 2 < NCH) a_nx2 = agp[(size_t)(ch + 2) * (32 * N_DIM)];
    if (ch + 1 < NCH) {
      // register prefetch for chunk ch+1 (consumed next step)
      const ushort* tn = fb + (size_t)(ch + 1) * (C_DIM * 32);
      nf0 = *(const bf16x8*)(tn + l15 * 32 + quad * 8);
      nf1 = *(const bf16x8*)(tn + (16 + l15) * 32 + quad * 8);
      *(f32x4*)&ne[0] = *(const f32x4*)(ekb + (ch + 1) * 32);
      *(f32x4*)&ne[4] = *(const f32x4*)(ekb + (ch + 1) * 32 + 4);
      // stage tile ch+1 into the other buffer (value loaded one chunk ago)
      grp[p ^ 1][swaddr] = a_nxt;
      a_nxt = a_nx2;
    }

    // adj fragment for this chunk: 2x ds_read_b128, bank-balanced
    float av[8];
    *(f32x4*)&av[0] = *(const f32x4*)&grp[p][l15 * 36 + quad * 8];
    *(f32x4*)&av[4] = *(const f32x4*)&grp[p][l15 * 36 + quad * 8 + 4];

    // w = adj * min(Ek,Em) * rcp(Ek+Em); pairwise-shared rcp
    uint4v wfu;
#pragma unroll
    for (int q = 0; q < 4; ++q) {
      const float e0 = ce[2 * q];
      const float e1 = ce[2 * q + 1];
      const float t0 = fminf(e0, Em);
      const float t1 = fminf(e1, Em);
      const float s0 = e0 + Em;
      const float s1 = e1 + Em;
      const float r = __builtin_amdgcn_rcpf(s0 * s1);
      const float w0 = av[2 * q] * t0 * (r * s1);
      const float w1 = av[2 * q + 1] * t1 * (r * s0);
      // truncating bf16x2 pack: bytes [w0.b2, w0.b3, w1.b2, w1.b3]
      wfu[q] = __builtin_amdgcn_perm(__float_as_uint(w1), __float_as_uint(w0),
                                     0x07060302u);
    }
    const bf16x8 wf = __builtin_bit_cast(bf16x8, wfu);

    acc0 = __builtin_amdgcn_mfma_f32_16x16x32_bf16(cf0, wf, acc0, 0, 0, 0);
    acc1 = __builtin_amdgcn_mfma_f32_16x16x32_bf16(cf1, wf, acc1, 0, 0, 0);

    // LDS-only wait + barrier: staged write visible, reads retired (WAR-safe),
    // prefetched global loads remain in flight.
    asm volatile("s_waitcnt lgkmcnt(0)\n\ts_barrier" ::: "memory");
  };

  for (int cb = 0; cb < NCH; cb += 2) {
    step(cb, 0, f0A, f1A, eA, f0B, f1B, eB);
    step(cb + 1, 1, f0B, f1B, eB, f0A, f1A, eA);
  }

  // fused kh-reduce + epilogue (D layout: col=l15, row=quad*4+r)
  if (kh == 1) {
#pragma unroll
    for (int r = 0; r < 4; ++r) {
      red[b][(quad * 4 + r) * 17 + l15] = acc0[r];
      red[b][(16 + quad * 4 + r) * 17 + l15] = acc1[r];
    }
  }
  __syncthreads();
  if (kh == 0) {
#pragma unroll
    for (int r = 0; r < 4; ++r) {
      const int c0 = quad * 4 + r;
      const int c1 = c0 + 16;
      float s0 = acc0[r] + red[b][c0 * 17 + l15];
      float s1 = acc1[r] + red[b][c1 * 17 + l15];
      s0 *= 2.0f * para[(size_t)c0 * N_DIM + col];   // x2: weight scale folded here
      s1 *= 2.0f * para[(size_t)c1 * N_DIM + col];
      out[((size_t)(b * C_DIM + c0)) * N_DIM + col] = fmaxf(s0, 0.f);
      out[((size_t)(b * C_DIM + c1)) * N_DIM + col] = fmaxf(s1, 0.f);
    }
  }
}

extern "C" void kernel_launch(void* const* d_in, const int* in_sizes, int n_in,
                              void* d_out, int out_size, void* d_ws, size_t ws_size,
                              hipStream_t stream) {
  const float* x = (const float*)d_in[0];     // [8,32,64,64]
  const float* para = (const float*)d_in[1];  // [1,32,64,64]
  const float* adj = (const float*)d_in[2];   // [4096,4096]
  float* out = (float*)d_out;

  // ws: E (128 KB) | feabT (2 MB) -- total 2.25 MB
  float* E = (float*)d_ws;
  ushort* feabT = (ushort*)(E + (size_t)B_DIM * N_DIM);

  prep_e<<<dim3(B_DIM * N_DIM / 256), dim3(256), 0, stream>>>(x, E);
  prep_feab<<<dim3(B_DIM * C_DIM * (N_DIM / 16) / 256), dim3(256), 0, stream>>>(x, feabT);
  gcn_fused<<<dim3(N_DIM / 16), dim3(1024), 0, stream>>>(feabT, adj, E, para, out);
}